// Round 6
// baseline (596.234 us; speedup 1.0000x reference)
//
#include <hip/hip_runtime.h>
#include <cstdint>

// GRU recurrent autoencoder, MI355X persistent-MFMA implementation, round 6.
// B=2048, T=128, X=38, H=128, 3H=384. fp32 I/O, fp16 MFMA operands,
// fp32 accumulation + fp32 recurrent state (in registers).
//
// Round-6 changes vs round 5 (which spilled ~70 regs/thread: VGPR_Count=128
// under (256,2) cap while 144 weight-frag VGPRs must be MFMA operands ->
// per-step L2 scratch reloads, WRITE_SIZE 75MB):
//  * NO predicated A-reads: A-row m feeds C-row m, and C rows !=0 mod 4 are
//    discarded, so every lane reads hrd[(mrow>>2)*HS2+...] unconditionally
//    (4-lane same-address groups broadcast = free; 2-way row aliasing =
//    free). x-frags likewise: garbage at k>=38 hits zero B-weights. Kills
//    all zero-vectors/cndmasks (~30 live regs + VALU).
//  * __launch_bounds__(256,1): lift the 256-reg cap; demand ~200 regs ->
//    allocator fits without spill, still 2 waves/SIMD -> 2 WGs/CU.
//  * Everything else identical to round 5 (verified correct, absmax 2e-3).

#define T_SEQ 128
#define X_DIM 38
#define H_DIM 128
#define B_TOT 2048
#define BT    4
#define HS2   160   // h row stride in halfs (>= H=128; 80 dw = 16 mod 32)
#define XSR   48    // x row stride in halfs (>= X=38; 24 dw)

typedef _Float16 half8 __attribute__((ext_vector_type(8)));
typedef float    f32x4 __attribute__((ext_vector_type(4)));

__device__ __forceinline__ float fast_sigmoid(float x) {
    return __builtin_amdgcn_rcpf(1.0f + __expf(-x));
}
__device__ __forceinline__ float fast_tanh(float x) {
    return 1.0f - 2.0f * __builtin_amdgcn_rcpf(1.0f + __expf(2.0f * x));
}

__global__ __launch_bounds__(256, 1)
void rae_gru_kernel(const float* __restrict__ x,
                    const float* __restrict__ eWih, const float* __restrict__ eWhh,
                    const float* __restrict__ ebih, const float* __restrict__ ebhh,
                    const float* __restrict__ dWih, const float* __restrict__ dWhh,
                    const float* __restrict__ dbih, const float* __restrict__ dbhh,
                    const float* __restrict__ linW, const float* __restrict__ linb,
                    float* __restrict__ out)
{
    __shared__ _Float16 hbuf[2 * BT * HS2];        // 2560 B, h double buffer
    __shared__ _Float16 sbuf[2 * BT * XSR + 64];   // x stage + OOB slack for
                                                   // unconditional xa1 reads
    __shared__ _Float16 w2lds[H_DIM * H_DIM];      // 32 KB, weight-fold staging

    const int tid  = threadIdx.x;
    const int wv   = tid >> 6;        // 0..3
    const int ln   = tid & 63;
    const int quad = ln >> 4;         // C/D: batch index; A/B: k-group
    const int mrow = ln & 15;         // A: m-row / B,C: col-in-tile
    const int b0   = blockIdx.x * BT;
    const int arow = mrow >> 2;       // packed h row this A-lane reads
                                      // (rows m!=4b produce discarded C rows)

    for (int i = tid; i < 2 * BT * HS2; i += 256) hbuf[i] = (_Float16)0.0f;
    for (int i = tid; i < 2 * BT * XSR + 64; i += 256) sbuf[i] = (_Float16)0.0f;
    // stage x[:, t=0]: wave wv = batch row wv
    if (ln < X_DIM)
        sbuf[wv * XSR + ln] = (_Float16)x[((size_t)(b0 + wv) * T_SEQ) * X_DIM + ln];
    __syncthreads();

    // ---- column ownership: sub s -> col = wv*32 + s*16 + mrow ----
    int col[2], jc[2][3];
    #pragma unroll
    for (int s = 0; s < 2; ++s) {
        col[s] = wv * 32 + s * 16 + mrow;
        #pragma unroll
        for (int p = 0; p < 3; ++p) jc[s][p] = p * H_DIM + col[s];
    }

    // ---- persistent weight fragments ----
    half8 wh[2][3][4];    // enc: eWhh | dec: r/z combined, n pure dWhh
    half8 wxe[2][3][2];   // encoder Wih (K padded 38->64); dead after encoder
    half8 wxn[2][4];      // decoder n-gate W2
    half8 wl[4];          // linear head
    float b_r[2], b_z[2], b_ngi[2], b_ngh[2];

    // ---- encoder weights ----
    #pragma unroll
    for (int s = 0; s < 2; ++s) {
        #pragma unroll
        for (int p = 0; p < 3; ++p) {
            const float* wr = eWhh + (size_t)jc[s][p] * H_DIM;
            #pragma unroll
            for (int c = 0; c < 4; ++c) {
                const int kb = c * 32 + quad * 8;
                half8 v;
                #pragma unroll
                for (int e = 0; e < 8; ++e) v[e] = (_Float16)wr[kb + e];
                wh[s][p][c] = v;
            }
            const float* wir = eWih + (size_t)jc[s][p] * X_DIM;
            #pragma unroll
            for (int c = 0; c < 2; ++c) {
                const int kb = c * 32 + quad * 8;
                half8 v;
                #pragma unroll
                for (int e = 0; e < 8; ++e) {
                    const int k = kb + e;
                    v[e] = (k < X_DIM) ? (_Float16)wir[k] : (_Float16)0.0f;
                }
                wxe[s][p][c] = v;
            }
        }
        b_r[s]   = ebih[jc[s][0]] + ebhh[jc[s][0]];
        b_z[s]   = ebih[jc[s][1]] + ebhh[jc[s][1]];
        b_ngi[s] = ebih[jc[s][2]];
        b_ngh[s] = ebhh[jc[s][2]];
    }

    float hold[2] = {0.0f, 0.0f};   // h[batch=quad][col[s]] in fp32

    // ================= encoder (1 barrier/step) =================
    #pragma unroll 1
    for (int t = 0; t < T_SEQ; ++t) {
        float xnext = 0.0f;
        const bool pf = (t + 1 < T_SEQ) && (ln < X_DIM);
        if (pf) xnext = x[((size_t)(b0 + wv) * T_SEQ + (t + 1)) * X_DIM + ln];

        const _Float16* hrd = hbuf + (t & 1) * (BT * HS2);
        _Float16*       hwr = hbuf + ((t & 1) ^ 1) * (BT * HS2);
        const _Float16* sb  = sbuf + (t & 1) * (BT * XSR);

        half8 ha[4];
        #pragma unroll
        for (int c = 0; c < 4; ++c)
            ha[c] = *(const half8*)&hrd[arow * HS2 + c * 32 + quad * 8];
        // xa1 for quad>0 reads junk at k>=40 -> multiplied by zero B weights
        half8 xa0 = *(const half8*)&sb[arow * XSR + quad * 8];
        half8 xa1 = *(const half8*)&sb[arow * XSR + 32 + quad * 8];

        #pragma unroll
        for (int s = 0; s < 2; ++s) {
            f32x4 ar = { b_r[s], b_r[s], b_r[s], b_r[s] };
            #pragma unroll
            for (int c = 0; c < 4; ++c)
                ar = __builtin_amdgcn_mfma_f32_16x16x32_f16(ha[c], wh[s][0][c], ar, 0, 0, 0);
            ar = __builtin_amdgcn_mfma_f32_16x16x32_f16(xa0, wxe[s][0][0], ar, 0, 0, 0);
            ar = __builtin_amdgcn_mfma_f32_16x16x32_f16(xa1, wxe[s][0][1], ar, 0, 0, 0);

            f32x4 az = { b_z[s], b_z[s], b_z[s], b_z[s] };
            #pragma unroll
            for (int c = 0; c < 4; ++c)
                az = __builtin_amdgcn_mfma_f32_16x16x32_f16(ha[c], wh[s][1][c], az, 0, 0, 0);
            az = __builtin_amdgcn_mfma_f32_16x16x32_f16(xa0, wxe[s][1][0], az, 0, 0, 0);
            az = __builtin_amdgcn_mfma_f32_16x16x32_f16(xa1, wxe[s][1][1], az, 0, 0, 0);

            f32x4 aghn = { b_ngh[s], b_ngh[s], b_ngh[s], b_ngh[s] };
            #pragma unroll
            for (int c = 0; c < 4; ++c)
                aghn = __builtin_amdgcn_mfma_f32_16x16x32_f16(ha[c], wh[s][2][c], aghn, 0, 0, 0);
            f32x4 agin = { b_ngi[s], b_ngi[s], b_ngi[s], b_ngi[s] };
            agin = __builtin_amdgcn_mfma_f32_16x16x32_f16(xa0, wxe[s][2][0], agin, 0, 0, 0);
            agin = __builtin_amdgcn_mfma_f32_16x16x32_f16(xa1, wxe[s][2][1], agin, 0, 0, 0);

            // epilogue: only reg 0 is a real row (batch = quad)
            const float r = fast_sigmoid(ar[0]);
            const float z = fast_sigmoid(az[0]);
            const float n = fast_tanh(agin[0] + r * aghn[0]);
            const float h = n + z * (hold[s] - n);
            hold[s] = h;
            hwr[quad * HS2 + col[s]] = (_Float16)h;
        }

        if (pf) sbuf[((t + 1) & 1) * (BT * XSR) + wv * XSR + ln] = (_Float16)xnext;
        __syncthreads();
    }

    // ================= decoder weight prep =================
    // Step A: pure dWhh frags + biases.
    float c_r0[2], c_z0[2], c_n0[2];
    #pragma unroll
    for (int s = 0; s < 2; ++s) {
        #pragma unroll
        for (int p = 0; p < 3; ++p) {
            const float* wr = dWhh + (size_t)jc[s][p] * H_DIM;
            #pragma unroll
            for (int c = 0; c < 4; ++c) {
                const int kb = c * 32 + quad * 8;
                half8 v;
                #pragma unroll
                for (int e = 0; e < 8; ++e) v[e] = (_Float16)wr[kb + e];
                wh[s][p][c] = v;
            }
        }
        c_r0[s] = dbih[jc[s][0]] + dbhh[jc[s][0]];
        c_z0[s] = dbih[jc[s][1]] + dbhh[jc[s][1]];
        c_n0[s] = dbih[jc[s][2]];
        b_ngh[s] = dbhh[jc[s][2]];
    }

    // Step B: t=0 pre-step (gi = bias only). h_enc in hbuf[0] -> d_1 to hbuf[1].
    {
        const _Float16* hrd = hbuf;
        _Float16*       hwr = hbuf + BT * HS2;
        half8 ha[4];
        #pragma unroll
        for (int c = 0; c < 4; ++c)
            ha[c] = *(const half8*)&hrd[arow * HS2 + c * 32 + quad * 8];
        #pragma unroll
        for (int s = 0; s < 2; ++s) {
            f32x4 ar = { c_r0[s], c_r0[s], c_r0[s], c_r0[s] };
            f32x4 az = { c_z0[s], c_z0[s], c_z0[s], c_z0[s] };
            f32x4 aghn = { b_ngh[s], b_ngh[s], b_ngh[s], b_ngh[s] };
            #pragma unroll
            for (int c = 0; c < 4; ++c) {
                ar   = __builtin_amdgcn_mfma_f32_16x16x32_f16(ha[c], wh[s][0][c], ar, 0, 0, 0);
                az   = __builtin_amdgcn_mfma_f32_16x16x32_f16(ha[c], wh[s][1][c], az, 0, 0, 0);
                aghn = __builtin_amdgcn_mfma_f32_16x16x32_f16(ha[c], wh[s][2][c], aghn, 0, 0, 0);
            }
            const float r = fast_sigmoid(ar[0]);
            const float z = fast_sigmoid(az[0]);
            const float n = fast_tanh(c_n0[s] + r * aghn[0]);
            const float h = n + z * (hold[s] - n);
            hold[s] = h;
            hwr[quad * HS2 + col[s]] = (_Float16)h;
        }
    }
    __syncthreads();

    // Step C: fold W2 = dWih*linW. r/z: wh <- fp16(dWhh + W2); n: wxn <- fp16(W2).
    {
        const int kk = ((wv & 1) << 6) | ln;      // 0..127, lane's column
        const int jb = (wv >> 1) * 64;            // waves {0,1}: rows 0..63, {2,3}: 64..127
        float lc[X_DIM];
        #pragma unroll
        for (int m = 0; m < X_DIM; ++m) lc[m] = linW[m * H_DIM + kk];

        // gate 0 (r): combined
        #pragma unroll 1
        for (int jj = 0; jj < 64; ++jj) {
            const int j = __builtin_amdgcn_readfirstlane(jb + jj);
            const float* dwr = dWih + (size_t)j * X_DIM;
            float sacc = dWhh[(size_t)j * H_DIM + kk];
            #pragma unroll
            for (int m = 0; m < X_DIM; ++m) sacc += dwr[m] * lc[m];
            w2lds[j * H_DIM + kk] = (_Float16)sacc;
        }
        __syncthreads();
        #pragma unroll
        for (int s = 0; s < 2; ++s)
            #pragma unroll
            for (int c = 0; c < 4; ++c)
                wh[s][0][c] = *(const half8*)&w2lds[col[s] * H_DIM + c * 32 + quad * 8];
        __syncthreads();

        // gate 1 (z): combined
        #pragma unroll 1
        for (int jj = 0; jj < 64; ++jj) {
            const int j = __builtin_amdgcn_readfirstlane(jb + jj);
            const float* dwr = dWih + (size_t)(H_DIM + j) * X_DIM;
            float sacc = dWhh[(size_t)(H_DIM + j) * H_DIM + kk];
            #pragma unroll
            for (int m = 0; m < X_DIM; ++m) sacc += dwr[m] * lc[m];
            w2lds[j * H_DIM + kk] = (_Float16)sacc;
        }
        __syncthreads();
        #pragma unroll
        for (int s = 0; s < 2; ++s)
            #pragma unroll
            for (int c = 0; c < 4; ++c)
                wh[s][1][c] = *(const half8*)&w2lds[col[s] * H_DIM + c * 32 + quad * 8];
        __syncthreads();

        // gate 2 (n): W2 only (wh[.][2] stays pure dWhh)
        #pragma unroll 1
        for (int jj = 0; jj < 64; ++jj) {
            const int j = __builtin_amdgcn_readfirstlane(jb + jj);
            const float* dwr = dWih + (size_t)(2 * H_DIM + j) * X_DIM;
            float sacc = 0.0f;
            #pragma unroll
            for (int m = 0; m < X_DIM; ++m) sacc += dwr[m] * lc[m];
            w2lds[j * H_DIM + kk] = (_Float16)sacc;
        }
        __syncthreads();
        #pragma unroll
        for (int s = 0; s < 2; ++s)
            #pragma unroll
            for (int c = 0; c < 4; ++c)
                wxn[s][c] = *(const half8*)&w2lds[col[s] * H_DIM + c * 32 + quad * 8];
        __syncthreads();
    }

    // Step D: linear head frags + folded biases for t>=1.
    const int nlin = wv * 16 + mrow;          // waves 0..2 cover cols 0..47
    const bool nv = (wv < 3) && (nlin < X_DIM);
    float lb = 0.0f;
    {
        const float* lr = linW + (size_t)(nv ? nlin : 0) * H_DIM;
        #pragma unroll
        for (int c = 0; c < 4; ++c) {
            const int kb = c * 32 + quad * 8;
            half8 v;
            #pragma unroll
            for (int e = 0; e < 8; ++e)
                v[e] = nv ? (_Float16)lr[kb + e] : (_Float16)0.0f;
            wl[c] = v;
        }
        if (nv) lb = linb[nlin];
    }
    #pragma unroll
    for (int s = 0; s < 2; ++s) {
        float bf[3];
        #pragma unroll
        for (int p = 0; p < 3; ++p) {
            const float* dwr = dWih + (size_t)jc[s][p] * X_DIM;
            float sacc = 0.0f;
            #pragma unroll
            for (int m = 0; m < X_DIM; ++m) sacc += linb[m] * dwr[m];
            bf[p] = sacc;
        }
        b_r[s]   = c_r0[s] + bf[0];
        b_z[s]   = c_z0[s] + bf[1];
        b_ngi[s] = c_n0[s] + bf[2];
    }

    // ================= decoder (t=1..127, 1 barrier/step) =================
    #pragma unroll 1
    for (int t = 1; t < T_SEQ; ++t) {
        const _Float16* hrd = hbuf + (t & 1) * (BT * HS2);
        _Float16*       hwr = hbuf + ((t & 1) ^ 1) * (BT * HS2);

        half8 ha[4];
        #pragma unroll
        for (int c = 0; c < 4; ++c)
            ha[c] = *(const half8*)&hrd[arow * HS2 + c * 32 + quad * 8];

        // overlapped output projection: o_{t-1} = d_t @ linW^T + lb
        if (wv < 3) {
            f32x4 al = { lb, lb, lb, lb };
            #pragma unroll
            for (int c = 0; c < 4; ++c)
                al = __builtin_amdgcn_mfma_f32_16x16x32_f16(ha[c], wl[c], al, 0, 0, 0);
            if (nv)
                out[((size_t)(b0 + quad) * T_SEQ + (t - 1)) * X_DIM + nlin] = al[0];
        }

        #pragma unroll
        for (int s = 0; s < 2; ++s) {
            f32x4 ar = { b_r[s], b_r[s], b_r[s], b_r[s] };
            #pragma unroll
            for (int c = 0; c < 4; ++c)
                ar = __builtin_amdgcn_mfma_f32_16x16x32_f16(ha[c], wh[s][0][c], ar, 0, 0, 0);
            f32x4 az = { b_z[s], b_z[s], b_z[s], b_z[s] };
            #pragma unroll
            for (int c = 0; c < 4; ++c)
                az = __builtin_amdgcn_mfma_f32_16x16x32_f16(ha[c], wh[s][1][c], az, 0, 0, 0);
            f32x4 aghn = { b_ngh[s], b_ngh[s], b_ngh[s], b_ngh[s] };
            #pragma unroll
            for (int c = 0; c < 4; ++c)
                aghn = __builtin_amdgcn_mfma_f32_16x16x32_f16(ha[c], wh[s][2][c], aghn, 0, 0, 0);
            f32x4 agin = { b_ngi[s], b_ngi[s], b_ngi[s], b_ngi[s] };
            #pragma unroll
            for (int c = 0; c < 4; ++c)
                agin = __builtin_amdgcn_mfma_f32_16x16x32_f16(ha[c], wxn[s][c], agin, 0, 0, 0);

            const float r = fast_sigmoid(ar[0]);
            const float z = fast_sigmoid(az[0]);
            const float n = fast_tanh(agin[0] + r * aghn[0]);
            const float h = n + z * (hold[s] - n);
            hold[s] = h;
            hwr[quad * HS2 + col[s]] = (_Float16)h;
        }
        __syncthreads();
    }

    // tail projection: o_{T-1} = d_128 @ linW^T + lb (d_128 in hbuf[0])
    if (wv < 3) {
        const _Float16* hrd = hbuf;
        half8 ha[4];
        #pragma unroll
        for (int c = 0; c < 4; ++c)
            ha[c] = *(const half8*)&hrd[arow * HS2 + c * 32 + quad * 8];
        f32x4 al = { lb, lb, lb, lb };
        #pragma unroll
        for (int c = 0; c < 4; ++c)
            al = __builtin_amdgcn_mfma_f32_16x16x32_f16(ha[c], wl[c], al, 0, 0, 0);
        if (nv)
            out[((size_t)(b0 + quad) * T_SEQ + (T_SEQ - 1)) * X_DIM + nlin] = al[0];
    }
}

extern "C" void kernel_launch(void* const* d_in, const int* in_sizes, int n_in,
                              void* d_out, int out_size, void* d_ws, size_t ws_size,
                              hipStream_t stream) {
    (void)in_sizes; (void)n_in; (void)d_ws; (void)ws_size; (void)out_size;
    const float* x    = (const float*)d_in[0];
    const float* eWih = (const float*)d_in[1];
    const float* eWhh = (const float*)d_in[2];
    const float* ebih = (const float*)d_in[3];
    const float* ebhh = (const float*)d_in[4];
    const float* dWih = (const float*)d_in[5];
    const float* dWhh = (const float*)d_in[6];
    const float* dbih = (const float*)d_in[7];
    const float* dbhh = (const float*)d_in[8];
    const float* linW = (const float*)d_in[9];
    const float* linb = (const float*)d_in[10];
    float* out = (float*)d_out;

    rae_gru_kernel<<<dim3(B_TOT / BT), dim3(256), 0, stream>>>(
        x, eWih, eWhh, ebih, ebhh, dWih, dWhh, dbih, dbhh, linW, linb, out);
}

// Round 7
// 361.490 us; speedup vs baseline: 1.6494x; 1.6494x over previous
//
#include <hip/hip_runtime.h>
#include <cstdint>

// GRU recurrent autoencoder, MI355X persistent-MFMA implementation, round 7.
// B=2048, T=128, X=38, H=128, 3H=384. fp32 I/O, fp16 MFMA operands,
// fp32 accumulation + fp32 recurrent state (in registers).
//
// Round-7 restructure vs round 6 (which lost co-residency: 168+ total regs >
// 256 -> 1 wave/SIMD -> grid 512 ran as 2 sequential batches; AND all rounds
// paid ~900-cyc HBM drain per step: __syncthreads emits s_waitcnt vmcnt(0)
// before s_barrier, draining the x prefetch load / out store every step):
//  * RAW BARRIER (s_waitcnt lgkmcnt(0); s_barrier, "memory" clobber): only
//    LDS is drained; global x loads and out stores stay in flight across
//    steps. No __syncthreads in the main loops.
//  * x never staged in LDS: each lane register-prefetches its 8 x-values
//    (aligned float2 loads, one step ahead) directly from global; quads 1-3
//    get xa1=xa0 (annihilated by zero weights). No staging writes at all.
//  * 512 thr, BT=8, grid 256 -> structurally 1 WG/CU, 8 waves = 2/SIMD;
//    __launch_bounds__(512,2) enforces <=256 regs at compile time.
//  * Batch row b at M-row 2b: valid C regs {0,2} -> 6 trans/lane/step; odd
//    A-rows read duplicate batch rows (finite, discarded C rows).
//  * 1 col-triple (r,z,n) per wave: weights 80 VGPRs (wh 48 + wxn 16 + wl 16).
//  * Decoder algebra as verified in r3/r5/r6: r/z combined (dWhh+dWih*linW),
//    n-gate W2 separate, projection overlapped, t=0 pre-step.

#define T_SEQ 128
#define X_DIM 38
#define H_DIM 128
#define B_TOT 2048
#define BT    8
#define HS    136   // h row stride in halfs (>=128; 68 dw -> good bank spread)

typedef _Float16 half8 __attribute__((ext_vector_type(8)));
typedef float    f32x4 __attribute__((ext_vector_type(4)));

__device__ __forceinline__ float fast_sigmoid(float x) {
    return __builtin_amdgcn_rcpf(1.0f + __expf(-x));
}
__device__ __forceinline__ float fast_tanh(float x) {
    return 1.0f - 2.0f * __builtin_amdgcn_rcpf(1.0f + __expf(2.0f * x));
}

// LDS-only barrier: no vmcnt drain -> global ops pipeline across steps.
#define LDS_BARRIER() asm volatile("s_waitcnt lgkmcnt(0)\n\ts_barrier" ::: "memory")

__global__ __launch_bounds__(512, 2)
void rae_gru_kernel(const float* __restrict__ x,
                    const float* __restrict__ eWih, const float* __restrict__ eWhh,
                    const float* __restrict__ ebih, const float* __restrict__ ebhh,
                    const float* __restrict__ dWih, const float* __restrict__ dWhh,
                    const float* __restrict__ dbih, const float* __restrict__ dbhh,
                    const float* __restrict__ linW, const float* __restrict__ linb,
                    float* __restrict__ out)
{
    __shared__ _Float16 hbuf[2 * BT * HS];       // 4352 B, h double buffer
    __shared__ _Float16 w2lds[H_DIM * H_DIM];    // 32 KB, weight-fold staging

    const int tid  = threadIdx.x;
    const int wv   = tid >> 6;        // 0..7
    const int ln   = tid & 63;
    const int quad = ln >> 4;         // A/B: k-group; C/D: row-group
    const int mrow = ln & 15;         // A: m-row / B,C: col-in-tile
    const int b0   = blockIdx.x * BT;
    const int arow = mrow >> 1;       // batch row this A-lane reads (b at m=2b)
    const int j    = wv * 16 + mrow;  // this lane's gate column (8 waves x 16)
    const int jc0  = j, jc1 = H_DIM + j, jc2 = 2 * H_DIM + j;

    {   // zero h state (h0 = 0)
        uint32_t* hz = (uint32_t*)hbuf;
        for (int i = tid; i < (2 * BT * HS) / 2; i += 512) hz[i] = 0u;
    }
    __syncthreads();

    // ---- persistent weight fragments (1 triple per wave) ----
    half8 wh[3][4];    // enc: eWhh | dec: r/z combined, n pure dWhh
    half8 wxe[3][2];   // encoder Wih (K padded 38->64); dead after encoder
    half8 wxn[4];      // decoder n-gate W2
    half8 wl[4];       // linear head
    float b_r, b_z, b_ngi, b_ngh;

    // ---- encoder weights ----
    #pragma unroll
    for (int p = 0; p < 3; ++p) {
        const int jp = p * H_DIM + j;
        const float* wr = eWhh + (size_t)jp * H_DIM;
        #pragma unroll
        for (int c = 0; c < 4; ++c) {
            const int kb = c * 32 + quad * 8;
            half8 v;
            #pragma unroll
            for (int e = 0; e < 8; ++e) v[e] = (_Float16)wr[kb + e];
            wh[p][c] = v;
        }
        const float* wir = eWih + (size_t)jp * X_DIM;
        #pragma unroll
        for (int c = 0; c < 2; ++c) {
            const int kb = c * 32 + quad * 8;
            half8 v;
            #pragma unroll
            for (int e = 0; e < 8; ++e) {
                const int k = kb + e;
                v[e] = (k < X_DIM) ? (_Float16)wir[k] : (_Float16)0.0f;
            }
            wxe[p][c] = v;
        }
    }
    b_r   = ebih[jc0] + ebhh[jc0];
    b_z   = ebih[jc1] + ebhh[jc1];
    b_ngi = ebih[jc2];
    b_ngh = ebhh[jc2];

    float hold[2] = {0.0f, 0.0f};   // h[2quad+e][j] in fp32

    // register x pipeline: lane's 8 x-values (k=8quad..+7) + quad0's k=32..37.
    // float2 loads: addr (38*row + even)*4 B -> 8-byte aligned always.
    float xc0[8], xc1[6], xn0[8], xn1[6];
    #pragma unroll
    for (int e = 0; e < 6; ++e) { xc1[e] = 0.0f; xn1[e] = 0.0f; }
    {
        const float* xr = x + ((size_t)(b0 + arow) * T_SEQ + 0) * X_DIM;
        #pragma unroll
        for (int u = 0; u < 4; ++u) {
            float2 w = *(const float2*)(xr + quad * 8 + 2 * u);
            xc0[2 * u] = w.x; xc0[2 * u + 1] = w.y;
        }
        if (quad == 0) {
            #pragma unroll
            for (int u = 0; u < 3; ++u) {
                float2 w = *(const float2*)(xr + 32 + 2 * u);
                xc1[2 * u] = w.x; xc1[2 * u + 1] = w.y;
            }
        }
    }

    // ================= encoder (raw LDS barrier per step) =================
    #pragma unroll 1
    for (int t = 0; t < T_SEQ; ++t) {
        // prefetch x for t+1 (stays in flight; no barrier drain)
        if (t + 1 < T_SEQ) {
            const float* xr = x + ((size_t)(b0 + arow) * T_SEQ + (t + 1)) * X_DIM;
            #pragma unroll
            for (int u = 0; u < 4; ++u) {
                float2 w = *(const float2*)(xr + quad * 8 + 2 * u);
                xn0[2 * u] = w.x; xn0[2 * u + 1] = w.y;
            }
            if (quad == 0) {
                #pragma unroll
                for (int u = 0; u < 3; ++u) {
                    float2 w = *(const float2*)(xr + 32 + 2 * u);
                    xn1[2 * u] = w.x; xn1[2 * u + 1] = w.y;
                }
            }
        }

        const _Float16* hrd = hbuf + (t & 1) * (BT * HS);
        _Float16*       hwr = hbuf + ((t & 1) ^ 1) * (BT * HS);

        half8 ha[4];
        #pragma unroll
        for (int c = 0; c < 4; ++c)
            ha[c] = *(const half8*)&hrd[arow * HS + c * 32 + quad * 8];

        half8 xa0, xa1;
        #pragma unroll
        for (int e = 0; e < 8; ++e) xa0[e] = (_Float16)xc0[e];
        xa1 = xa0;                     // quads 1-3: hits all-zero weights
        if (quad == 0) {
            #pragma unroll
            for (int e = 0; e < 6; ++e) xa1[e] = (_Float16)xc1[e];
            xa1[6] = (_Float16)0.0f; xa1[7] = (_Float16)0.0f;
        }

        // split gi (2-chain) / gh (4-chain) accumulators -> shorter dep chains
        f32x4 gir = { b_r, b_r, b_r, b_r };
        gir = __builtin_amdgcn_mfma_f32_16x16x32_f16(xa0, wxe[0][0], gir, 0, 0, 0);
        gir = __builtin_amdgcn_mfma_f32_16x16x32_f16(xa1, wxe[0][1], gir, 0, 0, 0);
        f32x4 giz = { b_z, b_z, b_z, b_z };
        giz = __builtin_amdgcn_mfma_f32_16x16x32_f16(xa0, wxe[1][0], giz, 0, 0, 0);
        giz = __builtin_amdgcn_mfma_f32_16x16x32_f16(xa1, wxe[1][1], giz, 0, 0, 0);
        f32x4 gin = { b_ngi, b_ngi, b_ngi, b_ngi };
        gin = __builtin_amdgcn_mfma_f32_16x16x32_f16(xa0, wxe[2][0], gin, 0, 0, 0);
        gin = __builtin_amdgcn_mfma_f32_16x16x32_f16(xa1, wxe[2][1], gin, 0, 0, 0);

        f32x4 ghr = { 0.0f, 0.0f, 0.0f, 0.0f };
        f32x4 ghz = { 0.0f, 0.0f, 0.0f, 0.0f };
        f32x4 ghn = { b_ngh, b_ngh, b_ngh, b_ngh };
        #pragma unroll
        for (int c = 0; c < 4; ++c) {
            ghr = __builtin_amdgcn_mfma_f32_16x16x32_f16(ha[c], wh[0][c], ghr, 0, 0, 0);
            ghz = __builtin_amdgcn_mfma_f32_16x16x32_f16(ha[c], wh[1][c], ghz, 0, 0, 0);
            ghn = __builtin_amdgcn_mfma_f32_16x16x32_f16(ha[c], wh[2][c], ghn, 0, 0, 0);
        }

        #pragma unroll
        for (int e = 0; e < 2; ++e) {
            const int rg = 2 * e;      // valid C rows: reg 0 -> b=2quad, reg 2 -> 2quad+1
            const float r = fast_sigmoid(gir[rg] + ghr[rg]);
            const float z = fast_sigmoid(giz[rg] + ghz[rg]);
            const float n = fast_tanh(gin[rg] + r * ghn[rg]);
            const float h = n + z * (hold[e] - n);
            hold[e] = h;
            hwr[(2 * quad + e) * HS + j] = (_Float16)h;
        }

        // rotate x pipeline (register moves; vmcnt waited here, ~1 step of cover)
        #pragma unroll
        for (int e = 0; e < 8; ++e) xc0[e] = xn0[e];
        if (quad == 0) {
            #pragma unroll
            for (int e = 0; e < 6; ++e) xc1[e] = xn1[e];
        }

        LDS_BARRIER();
    }

    // ================= decoder weight prep =================
    // Step A: pure dWhh frags + biases.
    #pragma unroll
    for (int p = 0; p < 3; ++p) {
        const float* wr = dWhh + (size_t)(p * H_DIM + j) * H_DIM;
        #pragma unroll
        for (int c = 0; c < 4; ++c) {
            const int kb = c * 32 + quad * 8;
            half8 v;
            #pragma unroll
            for (int e = 0; e < 8; ++e) v[e] = (_Float16)wr[kb + e];
            wh[p][c] = v;
        }
    }
    const float c_r0 = dbih[jc0] + dbhh[jc0];
    const float c_z0 = dbih[jc1] + dbhh[jc1];
    const float c_n0 = dbih[jc2];
    b_ngh = dbhh[jc2];

    // Step B: t=0 pre-step (gi = bias only). h_enc in hbuf[0] -> d_1 to hbuf[1].
    {
        const _Float16* hrd = hbuf;
        _Float16*       hwr = hbuf + BT * HS;
        half8 ha[4];
        #pragma unroll
        for (int c = 0; c < 4; ++c)
            ha[c] = *(const half8*)&hrd[arow * HS + c * 32 + quad * 8];
        f32x4 ar = { c_r0, c_r0, c_r0, c_r0 };
        f32x4 az = { c_z0, c_z0, c_z0, c_z0 };
        f32x4 aghn = { b_ngh, b_ngh, b_ngh, b_ngh };
        #pragma unroll
        for (int c = 0; c < 4; ++c) {
            ar   = __builtin_amdgcn_mfma_f32_16x16x32_f16(ha[c], wh[0][c], ar, 0, 0, 0);
            az   = __builtin_amdgcn_mfma_f32_16x16x32_f16(ha[c], wh[1][c], az, 0, 0, 0);
            aghn = __builtin_amdgcn_mfma_f32_16x16x32_f16(ha[c], wh[2][c], aghn, 0, 0, 0);
        }
        #pragma unroll
        for (int e = 0; e < 2; ++e) {
            const int rg = 2 * e;
            const float r = fast_sigmoid(ar[rg]);
            const float z = fast_sigmoid(az[rg]);
            const float n = fast_tanh(c_n0 + r * aghn[rg]);
            const float h = n + z * (hold[e] - n);
            hold[e] = h;
            hwr[(2 * quad + e) * HS + j] = (_Float16)h;
        }
    }
    __syncthreads();

    // Step C: fold W2 = dWih*linW. r/z: wh <- fp16(dWhh + W2); n: wxn <- fp16(W2).
    {
        const int kk = ((wv & 1) << 6) | ln;      // 0..127, lane's W2 column
        const int jb = (wv >> 1) * 32;            // 4 wave-pairs x 32 rows = 128
        float lc[X_DIM];
        #pragma unroll
        for (int m = 0; m < X_DIM; ++m) lc[m] = linW[m * H_DIM + kk];

        // gate 0 (r): combined
        #pragma unroll 1
        for (int jj = 0; jj < 32; ++jj) {
            const int jr = __builtin_amdgcn_readfirstlane(jb + jj);
            const float* dwr = dWih + (size_t)jr * X_DIM;
            float sacc = dWhh[(size_t)jr * H_DIM + kk];
            #pragma unroll
            for (int m = 0; m < X_DIM; ++m) sacc += dwr[m] * lc[m];
            w2lds[jr * H_DIM + kk] = (_Float16)sacc;
        }
        __syncthreads();
        #pragma unroll
        for (int c = 0; c < 4; ++c)
            wh[0][c] = *(const half8*)&w2lds[j * H_DIM + c * 32 + quad * 8];
        __syncthreads();

        // gate 1 (z): combined
        #pragma unroll 1
        for (int jj = 0; jj < 32; ++jj) {
            const int jr = __builtin_amdgcn_readfirstlane(jb + jj);
            const float* dwr = dWih + (size_t)(H_DIM + jr) * X_DIM;
            float sacc = dWhh[(size_t)(H_DIM + jr) * H_DIM + kk];
            #pragma unroll
            for (int m = 0; m < X_DIM; ++m) sacc += dwr[m] * lc[m];
            w2lds[jr * H_DIM + kk] = (_Float16)sacc;
        }
        __syncthreads();
        #pragma unroll
        for (int c = 0; c < 4; ++c)
            wh[1][c] = *(const half8*)&w2lds[j * H_DIM + c * 32 + quad * 8];
        __syncthreads();

        // gate 2 (n): W2 only (wh[2] stays pure dWhh)
        #pragma unroll 1
        for (int jj = 0; jj < 32; ++jj) {
            const int jr = __builtin_amdgcn_readfirstlane(jb + jj);
            const float* dwr = dWih + (size_t)(2 * H_DIM + jr) * X_DIM;
            float sacc = 0.0f;
            #pragma unroll
            for (int m = 0; m < X_DIM; ++m) sacc += dwr[m] * lc[m];
            w2lds[jr * H_DIM + kk] = (_Float16)sacc;
        }
        __syncthreads();
        #pragma unroll
        for (int c = 0; c < 4; ++c)
            wxn[c] = *(const half8*)&w2lds[j * H_DIM + c * 32 + quad * 8];
        __syncthreads();
    }

    // Step D: linear head frags + folded biases for t>=1.
    const int nlin = wv * 16 + mrow;          // waves 0..2 cover cols 0..47
    const bool nv = (wv < 3) && (nlin < X_DIM);
    float lb = 0.0f;
    {
        const float* lr = linW + (size_t)(nv ? nlin : 0) * H_DIM;
        #pragma unroll
        for (int c = 0; c < 4; ++c) {
            const int kb = c * 32 + quad * 8;
            half8 v;
            #pragma unroll
            for (int e = 0; e < 8; ++e)
                v[e] = nv ? (_Float16)lr[kb + e] : (_Float16)0.0f;
            wl[c] = v;
        }
        if (nv) lb = linb[nlin];
    }
    {
        float bf[3];
        #pragma unroll
        for (int p = 0; p < 3; ++p) {
            const float* dwr = dWih + (size_t)(p * H_DIM + j) * X_DIM;
            float sacc = 0.0f;
            #pragma unroll
            for (int m = 0; m < X_DIM; ++m) sacc += linb[m] * dwr[m];
            bf[p] = sacc;
        }
        b_r   = c_r0 + bf[0];
        b_z   = c_z0 + bf[1];
        b_ngi = c_n0 + bf[2];
    }

    // ================= decoder (t=1..127, raw LDS barrier per step) ========
    #pragma unroll 1
    for (int t = 1; t < T_SEQ; ++t) {
        const _Float16* hrd = hbuf + (t & 1) * (BT * HS);
        _Float16*       hwr = hbuf + ((t & 1) ^ 1) * (BT * HS);

        half8 ha[4];
        #pragma unroll
        for (int c = 0; c < 4; ++c)
            ha[c] = *(const half8*)&hrd[arow * HS + c * 32 + quad * 8];

        // overlapped output projection: o_{t-1} = d_t @ linW^T + lb
        // (stores stay in flight across the raw barrier)
        if (wv < 3) {
            f32x4 al = { lb, lb, lb, lb };
            #pragma unroll
            for (int c = 0; c < 4; ++c)
                al = __builtin_amdgcn_mfma_f32_16x16x32_f16(ha[c], wl[c], al, 0, 0, 0);
            if (nv) {
                out[((size_t)(b0 + 2 * quad)     * T_SEQ + (t - 1)) * X_DIM + nlin] = al[0];
                out[((size_t)(b0 + 2 * quad + 1) * T_SEQ + (t - 1)) * X_DIM + nlin] = al[2];
            }
        }

        f32x4 ar = { b_r, b_r, b_r, b_r };
        f32x4 az = { b_z, b_z, b_z, b_z };
        f32x4 aghn = { b_ngh, b_ngh, b_ngh, b_ngh };
        f32x4 agin = { b_ngi, b_ngi, b_ngi, b_ngi };
        #pragma unroll
        for (int c = 0; c < 4; ++c) {
            ar   = __builtin_amdgcn_mfma_f32_16x16x32_f16(ha[c], wh[0][c], ar, 0, 0, 0);
            az   = __builtin_amdgcn_mfma_f32_16x16x32_f16(ha[c], wh[1][c], az, 0, 0, 0);
            aghn = __builtin_amdgcn_mfma_f32_16x16x32_f16(ha[c], wh[2][c], aghn, 0, 0, 0);
            agin = __builtin_amdgcn_mfma_f32_16x16x32_f16(ha[c], wxn[c],  agin, 0, 0, 0);
        }

        #pragma unroll
        for (int e = 0; e < 2; ++e) {
            const int rg = 2 * e;
            const float r = fast_sigmoid(ar[rg]);
            const float z = fast_sigmoid(az[rg]);
            const float n = fast_tanh(agin[rg] + r * aghn[rg]);
            const float h = n + z * (hold[e] - n);
            hold[e] = h;
            hwr[(2 * quad + e) * HS + j] = (_Float16)h;
        }

        LDS_BARRIER();
    }

    // tail projection: o_{T-1} = d_128 @ linW^T + lb (d_128 in hbuf[0])
    if (wv < 3) {
        const _Float16* hrd = hbuf;
        half8 ha[4];
        #pragma unroll
        for (int c = 0; c < 4; ++c)
            ha[c] = *(const half8*)&hrd[arow * HS + c * 32 + quad * 8];
        f32x4 al = { lb, lb, lb, lb };
        #pragma unroll
        for (int c = 0; c < 4; ++c)
            al = __builtin_amdgcn_mfma_f32_16x16x32_f16(ha[c], wl[c], al, 0, 0, 0);
        if (nv) {
            out[((size_t)(b0 + 2 * quad)     * T_SEQ + (T_SEQ - 1)) * X_DIM + nlin] = al[0];
            out[((size_t)(b0 + 2 * quad + 1) * T_SEQ + (T_SEQ - 1)) * X_DIM + nlin] = al[2];
        }
    }
}

extern "C" void kernel_launch(void* const* d_in, const int* in_sizes, int n_in,
                              void* d_out, int out_size, void* d_ws, size_t ws_size,
                              hipStream_t stream) {
    (void)in_sizes; (void)n_in; (void)d_ws; (void)ws_size; (void)out_size;
    const float* x    = (const float*)d_in[0];
    const float* eWih = (const float*)d_in[1];
    const float* eWhh = (const float*)d_in[2];
    const float* ebih = (const float*)d_in[3];
    const float* ebhh = (const float*)d_in[4];
    const float* dWih = (const float*)d_in[5];
    const float* dWhh = (const float*)d_in[6];
    const float* dbih = (const float*)d_in[7];
    const float* dbhh = (const float*)d_in[8];
    const float* linW = (const float*)d_in[9];
    const float* linb = (const float*)d_in[10];
    float* out = (float*)d_out;

    rae_gru_kernel<<<dim3(B_TOT / BT), dim3(512), 0, stream>>>(
        x, eWih, eWhh, ebih, ebhh, dWih, dWhh, dbih, dbhh, linW, linb, out);
}